// Round 17
// baseline (673.660 us; speedup 1.0000x reference)
//
#include <hip/hip_runtime.h>

#define NPTS   8192
#define NBATCH 16
#define NGROUP 512
#define GSIZE  32
#define BIGF   1e10f

typedef unsigned long long u64;

// DPP max on a packed u64 key (round-7 proven).
template <int CTRL>
__device__ __forceinline__ u64 dpp_max_u64(u64 k) {
    const unsigned lo  = (unsigned)k;
    const unsigned hi  = (unsigned)(k >> 32);
    const unsigned slo = (unsigned)__builtin_amdgcn_update_dpp(0, (int)lo, CTRL, 0xF, 0xF, true);
    const unsigned shi = (unsigned)__builtin_amdgcn_update_dpp(0, (int)hi, CTRL, 0xF, 0xF, true);
    const u64 s = ((u64)shi << 32) | slo;
    return s > k ? s : k;
}

__device__ __forceinline__ u64 umax64(u64 a, u64 b) { return a > b ? a : b; }

// wave-uniform 64-bit readlane (SALU path, no LDS pipe)
__device__ __forceinline__ u64 rdlane64(u64 v, int l) {
    const unsigned lo = (unsigned)__builtin_amdgcn_readlane((int)(unsigned)v, l);
    const unsigned hi = (unsigned)__builtin_amdgcn_readlane((int)(unsigned)(v >> 32), l);
    return ((u64)hi << 32) | lo;
}

// ---------------------------------------------------------------------------
// knn scan for ONE query — r11 machinery (u64 keys = f64 bit order, readlane
// broadcasts, 2 points/lane/iter, lane-distributed sorted top-32) reading the
// block's LDS copy of the batch xyz. Bit-identical keys/order to r11.
// ---------------------------------------------------------------------------
__device__ __forceinline__ void knn_one(const float* __restrict__ base,
                                        const float4* sp,
                                        float* __restrict__ out,
                                        const int q, const int r, const int lane) {
    const float4 Q = sp[r];
    const float qxf = Q.x, qyf = Q.y, qzf = Q.z;
    const double qx = (double)qxf, qy = (double)qyf, qz = (double)qzf;

    const u64 INFB = 0x7ff0000000000000ull;
    u64 vk = INFB;  int vi = 0x7fffffff;
    u64 tauk = INFB;

    for (int i = 0; i < NPTS / 128; ++i) {
        const int p0 = i * 128 + lane;
        const float4 T0 = sp[p0];
        const float4 T1 = sp[p0 + 64];

        const double dx0 = qx - (double)T0.x;
        const double dy0 = qy - (double)T0.y;
        const double dz0 = qz - (double)T0.z;
        const u64 kd0 = __double_as_longlong(dx0 * dx0 + dy0 * dy0 + dz0 * dz0);
        const double dx1 = qx - (double)T1.x;
        const double dy1 = qy - (double)T1.y;
        const double dz1 = qz - (double)T1.z;
        const u64 kd1 = __double_as_longlong(dx1 * dx1 + dy1 * dy1 + dz1 * dz1);

        u64 m0 = __ballot(kd0 < tauk);
        const u64 m1pre = __ballot(kd1 < tauk);

        if (m0 | m1pre) {
            while (m0) {
                const int l = __ffsll(m0) - 1;
                m0 &= m0 - 1;
                const u64 xk = rdlane64(kd0, l);
                const int xi = i * 128 + l;
                const u64 pk = __shfl_up(vk, 1);
                const int pv = __shfl_up(vi, 1);
                const bool ltp = (lane > 0) && (xk < pk);
                const bool ltc = xk < vk;
                vk = ltp ? pk : (ltc ? xk : vk);
                vi = ltp ? pv : (ltc ? xi : vi);
            }
            tauk = rdlane64(vk, 31);
            u64 m1 = m1pre;
            while (m1) {
                const int l = __ffsll(m1) - 1;
                m1 &= m1 - 1;
                const u64 xk = rdlane64(kd1, l);
                if (xk < tauk) {
                    const int xi = i * 128 + 64 + l;
                    const u64 pk = __shfl_up(vk, 1);
                    const int pv = __shfl_up(vi, 1);
                    const bool ltp = (lane > 0) && (xk < pk);
                    const bool ltc = xk < vk;
                    vk = ltp ? pk : (ltc ? xk : vk);
                    vi = ltp ? pv : (ltc ? xi : vi);
                }
            }
            tauk = rdlane64(vk, 31);
        }
    }

    const size_t NBH = (size_t)NBATCH * NGROUP * GSIZE * 6;
    const size_t CEN = (size_t)NBATCH * NGROUP * 6;

    if (lane == 0) {
#pragma unroll
        for (int c = 0; c < 6; ++c)
            out[NBH + (size_t)q * 6 + c] = base[r * 6 + c];
    }
    if (lane < GSIZE) {
        const int n = vi;
        out[NBH + CEN + (size_t)q * GSIZE + lane] = (float)n;

        const float* np_ = base + (size_t)n * 6;
        const size_t o = ((size_t)q * GSIZE + lane) * 6;
        out[o + 0] = __fsub_rn(np_[0], qxf);
        out[o + 1] = __fsub_rn(np_[1], qyf);
        out[o + 2] = __fsub_rn(np_[2], qzf);
        out[o + 3] = np_[3];
        out[o + 4] = np_[4];
        out[o + 5] = np_[5];
    }
}

// ---------------------------------------------------------------------------
// Fused producer/consumer (r15/16 skeleton). 256 blocks x 512 thr, ~129KB LDS
// -> 1 block/CU, all co-resident.
// ROUND-17: watermark protocol decouples consumer polling from the producer's
// store-drain path. Producer: rep[k] RELAXED store each iter (uncontended);
// wm[b] RELEASE store every 8th iter (+ final). Consumers: ACQUIRE-poll
// wm[b] (one padded line per batch), then relaxed-read rep[q] — the
// release/acquire pair orders the rep stores. The r16 tax (~46us) was the
// producer's pre-barrier vmcnt(0) drain fighting 1920 pollers on the rep
// lines.
// ---------------------------------------------------------------------------
__global__ __launch_bounds__(512) void fused_kernel(const float* __restrict__ pc,
                                                    int* __restrict__ rep,
                                                    int* __restrict__ wm,
                                                    float* __restrict__ out) {
    const int bid  = blockIdx.x;
    const int t    = threadIdx.x;
    const int lane = t & 63;
    const int w    = t >> 6;

    __shared__ float4 sp[NPTS];                      // 128 KB
    __shared__ __align__(16) u64 keys[2][8];

    if (bid < NBATCH) {
        // ---------------- FPS producer (r11 body + publish) -----------------
        const int b = bid;
        const float* base = pc + (size_t)b * NPTS * 6;

        float px[16], py[16], pz[16], dmin[16];
#pragma unroll
        for (int j = 0; j < 16; ++j) {
            const int p = t * 16 + j;
            const float x = base[p * 6 + 0];
            const float y = base[p * 6 + 1];
            const float z = base[p * 6 + 2];
            px[j] = x; py[j] = y; pz[j] = z;
            sp[p] = make_float4(x, y, z, 0.0f);
            dmin[j] = BIGF;
        }
        __syncthreads();

        int last = 0;
        for (int k = 0; k < NGROUP; ++k) {
            if (t == 0) {
                __hip_atomic_store(rep + b * NGROUP + k, last,
                                   __ATOMIC_RELAXED, __HIP_MEMORY_SCOPE_AGENT);
                if ((k & 7) == 7 || k == NGROUP - 1)
                    __hip_atomic_store(wm + b * 16, k,
                                       __ATOMIC_RELEASE, __HIP_MEMORY_SCOPE_AGENT);
            }
            if (k == NGROUP - 1) break;

            const float4 L = sp[last];               // one ds_read_b128, broadcast

            float bv = -1.0f;
            int   bi = 0;
#pragma unroll
            for (int j = 0; j < 16; ++j) {
                const float dx = __fsub_rn(px[j], L.x);
                const float dy = __fsub_rn(py[j], L.y);
                const float dz = __fsub_rn(pz[j], L.z);
                // ((dx^2 + dy^2) + dz^2), no FMA -> matches numpy fp32 (verified)
                const float d = __fadd_rn(__fadd_rn(__fmul_rn(dx, dx),
                                                    __fmul_rn(dy, dy)),
                                          __fmul_rn(dz, dz));
                const float dm = fminf(dmin[j], d);
                dmin[j] = dm;
                if (dm > bv) { bv = dm; bi = t * 16 + j; }   // strict > keeps lowest idx
            }

            u64 key = ((u64)__float_as_uint(bv) << 13) | (unsigned)(8191 - bi);
            key = dpp_max_u64<0x111>(key);   // row_shr:1
            key = dpp_max_u64<0x112>(key);   // row_shr:2
            key = dpp_max_u64<0x114>(key);   // row_shr:4
            key = dpp_max_u64<0x118>(key);   // row_shr:8
            key = dpp_max_u64<0x142>(key);   // row_bcast:15
            key = dpp_max_u64<0x143>(key);   // row_bcast:31 -> lane 63 = wave max

            const int buf = k & 1;                   // parity dbuf -> 1 barrier/iter
            if (lane == 63) keys[buf][w] = key;
            __syncthreads();

            const ulonglong2* kp = (const ulonglong2*)keys[buf];   // 4x ds_read_b128
            const ulonglong2 k0 = kp[0], k1 = kp[1], k2 = kp[2], k3 = kp[3];
            const u64 best = umax64(umax64(umax64(k0.x, k0.y), umax64(k1.x, k1.y)),
                                    umax64(umax64(k2.x, k2.y), umax64(k3.x, k3.y)));
            last = 8191 - (int)(best & 0x1FFFull);
        }
    } else {
        // ---------------- KNN consumers -------------------------------------
        const int kb = bid - NBATCH;                 // 0..239
        const int b  = kb / 15;                      // batch
        const int j  = kb % 15;                      // block-in-batch
        const int m0 = j * 8 + w;                    // 0..119 (wave's first query)

        const float* base = pc + (size_t)b * NPTS * 6;

        // stage the whole batch's xyz into this block's LDS (idle time:
        // happens before fps publishes anything)
#pragma unroll
        for (int jj = 0; jj < NPTS / 512; ++jj) {
            const int p = jj * 512 + t;
            sp[p] = make_float4(base[p * 6 + 0], base[p * 6 + 1],
                                base[p * 6 + 2], 0.0f);
        }
        __syncthreads();

        for (int m = m0; m < NGROUP; m += 120) {
            const int q = b * NGROUP + m;
            for (;;) {
                const int wmv = __hip_atomic_load(wm + b * 16, __ATOMIC_ACQUIRE,
                                                  __HIP_MEMORY_SCOPE_AGENT);
                if (wmv >= m) break;
                __builtin_amdgcn_s_sleep(8);
            }
            const int rv = __hip_atomic_load(rep + q, __ATOMIC_RELAXED,
                                             __HIP_MEMORY_SCOPE_AGENT);
            knn_one(base, sp, out, q, rv, lane);
        }
    }
}

extern "C" void kernel_launch(void* const* d_in, const int* in_sizes, int n_in,
                              void* d_out, int out_size, void* d_ws, size_t ws_size,
                              hipStream_t stream) {
    const float* pc  = (const float*)d_in[0];
    float*       out = (float*)d_out;
    int*         rep = (int*)d_ws;                              // 32 KB
    int*         wm  = (int*)((char*)d_ws + 32 * 1024);         // 16 padded ints

    // wm = -1 sentinels (0xFF bytes) — stream op, graph-capture-safe.
    // rep needs no init: consumers read rep[q] only after wm >= m.
    hipMemsetAsync(wm, 0xFF, 16 * 16 * sizeof(int), stream);

    fused_kernel<<<NBATCH + 240, 512, 0, stream>>>(pc, rep, wm, out);
}

// Round 18
// 582.710 us; speedup vs baseline: 1.1561x; 1.1561x over previous
//
#include <hip/hip_runtime.h>

#define NPTS   8192
#define NBATCH 16
#define NGROUP 512
#define GSIZE  32
#define BIGF   1e10f

typedef unsigned long long u64;

// DPP max on a packed u64 key (round-7 proven).
template <int CTRL>
__device__ __forceinline__ u64 dpp_max_u64(u64 k) {
    const unsigned lo  = (unsigned)k;
    const unsigned hi  = (unsigned)(k >> 32);
    const unsigned slo = (unsigned)__builtin_amdgcn_update_dpp(0, (int)lo, CTRL, 0xF, 0xF, true);
    const unsigned shi = (unsigned)__builtin_amdgcn_update_dpp(0, (int)hi, CTRL, 0xF, 0xF, true);
    const u64 s = ((u64)shi << 32) | slo;
    return s > k ? s : k;
}

__device__ __forceinline__ u64 umax64(u64 a, u64 b) { return a > b ? a : b; }

// wave-uniform 64-bit readlane (SALU path, no LDS pipe)
__device__ __forceinline__ u64 rdlane64(u64 v, int l) {
    const unsigned lo = (unsigned)__builtin_amdgcn_readlane((int)(unsigned)v, l);
    const unsigned hi = (unsigned)__builtin_amdgcn_readlane((int)(unsigned)(v >> 32), l);
    return ((u64)hi << 32) | lo;
}

// ---------------------------------------------------------------------------
// knn scan for ONE query — r11 machinery (u64 keys = f64 bit order, readlane
// broadcasts, 2 points/lane/iter, lane-distributed sorted top-32) reading the
// block's LDS copy of the batch xyz. Bit-identical keys/order to r11.
// ---------------------------------------------------------------------------
__device__ __forceinline__ void knn_one(const float* __restrict__ base,
                                        const float4* sp,
                                        float* __restrict__ out,
                                        const int q, const int r, const int lane) {
    const float4 Q = sp[r];
    const float qxf = Q.x, qyf = Q.y, qzf = Q.z;
    const double qx = (double)qxf, qy = (double)qyf, qz = (double)qzf;

    const u64 INFB = 0x7ff0000000000000ull;
    u64 vk = INFB;  int vi = 0x7fffffff;
    u64 tauk = INFB;

    for (int i = 0; i < NPTS / 128; ++i) {
        const int p0 = i * 128 + lane;
        const float4 T0 = sp[p0];
        const float4 T1 = sp[p0 + 64];

        const double dx0 = qx - (double)T0.x;
        const double dy0 = qy - (double)T0.y;
        const double dz0 = qz - (double)T0.z;
        const u64 kd0 = __double_as_longlong(dx0 * dx0 + dy0 * dy0 + dz0 * dz0);
        const double dx1 = qx - (double)T1.x;
        const double dy1 = qy - (double)T1.y;
        const double dz1 = qz - (double)T1.z;
        const u64 kd1 = __double_as_longlong(dx1 * dx1 + dy1 * dy1 + dz1 * dz1);

        u64 m0 = __ballot(kd0 < tauk);
        const u64 m1pre = __ballot(kd1 < tauk);

        if (m0 | m1pre) {
            while (m0) {
                const int l = __ffsll(m0) - 1;
                m0 &= m0 - 1;
                const u64 xk = rdlane64(kd0, l);
                const int xi = i * 128 + l;
                const u64 pk = __shfl_up(vk, 1);
                const int pv = __shfl_up(vi, 1);
                const bool ltp = (lane > 0) && (xk < pk);
                const bool ltc = xk < vk;
                vk = ltp ? pk : (ltc ? xk : vk);
                vi = ltp ? pv : (ltc ? xi : vi);
            }
            tauk = rdlane64(vk, 31);
            u64 m1 = m1pre;
            while (m1) {
                const int l = __ffsll(m1) - 1;
                m1 &= m1 - 1;
                const u64 xk = rdlane64(kd1, l);
                if (xk < tauk) {
                    const int xi = i * 128 + 64 + l;
                    const u64 pk = __shfl_up(vk, 1);
                    const int pv = __shfl_up(vi, 1);
                    const bool ltp = (lane > 0) && (xk < pk);
                    const bool ltc = xk < vk;
                    vk = ltp ? pk : (ltc ? xk : vk);
                    vi = ltp ? pv : (ltc ? xi : vi);
                }
            }
            tauk = rdlane64(vk, 31);
        }
    }

    const size_t NBH = (size_t)NBATCH * NGROUP * GSIZE * 6;
    const size_t CEN = (size_t)NBATCH * NGROUP * 6;

    if (lane == 0) {
#pragma unroll
        for (int c = 0; c < 6; ++c)
            out[NBH + (size_t)q * 6 + c] = base[r * 6 + c];
    }
    if (lane < GSIZE) {
        const int n = vi;
        out[NBH + CEN + (size_t)q * GSIZE + lane] = (float)n;

        const float* np_ = base + (size_t)n * 6;
        const size_t o = ((size_t)q * GSIZE + lane) * 6;
        out[o + 0] = __fsub_rn(np_[0], qxf);
        out[o + 1] = __fsub_rn(np_[1], qyf);
        out[o + 2] = __fsub_rn(np_[2], qzf);
        out[o + 3] = np_[3];
        out[o + 4] = np_[4];
        out[o + 5] = np_[5];
    }
}

// ---------------------------------------------------------------------------
// Fused producer/consumer — r16 skeleton VERBATIM (582us best) except the
// poll backoff: s_sleep(8) -> s_sleep(127) (~3.4us, ISA max). Waiting waves
// were issuing ~550 GB/s of 64B poll transactions (waves wait ~90% of the
// kernel at 0.2us/poll); that fabric pressure was stretching the producer's
// per-iteration store drain. 16x fewer polls, <=3.4us added tail latency.
//  blocks 0..15  : fps producer (r11 body), rep[b][k] relaxed store per iter.
//  blocks 16..255: 15/batch, stage batch xyz to LDS, relaxed-poll rep[q],
//                  scan from LDS. 1 block/CU (129KB LDS) -> all co-resident.
// ---------------------------------------------------------------------------
__global__ __launch_bounds__(512) void fused_kernel(const float* __restrict__ pc,
                                                    int* __restrict__ rep,
                                                    float* __restrict__ out) {
    const int bid  = blockIdx.x;
    const int t    = threadIdx.x;
    const int lane = t & 63;
    const int w    = t >> 6;

    __shared__ float4 sp[NPTS];                      // 128 KB
    __shared__ __align__(16) u64 keys[2][8];

    if (bid < NBATCH) {
        // ---------------- FPS producer (r11 body + per-iter publish) --------
        const int b = bid;
        const float* base = pc + (size_t)b * NPTS * 6;

        float px[16], py[16], pz[16], dmin[16];
#pragma unroll
        for (int j = 0; j < 16; ++j) {
            const int p = t * 16 + j;
            const float x = base[p * 6 + 0];
            const float y = base[p * 6 + 1];
            const float z = base[p * 6 + 2];
            px[j] = x; py[j] = y; pz[j] = z;
            sp[p] = make_float4(x, y, z, 0.0f);
            dmin[j] = BIGF;
        }
        __syncthreads();

        int last = 0;
        for (int k = 0; k < NGROUP; ++k) {
            if (t == 0)
                __hip_atomic_store(rep + b * NGROUP + k, last,
                                   __ATOMIC_RELAXED, __HIP_MEMORY_SCOPE_AGENT);
            if (k == NGROUP - 1) break;

            const float4 L = sp[last];               // one ds_read_b128, broadcast

            float bv = -1.0f;
            int   bi = 0;
#pragma unroll
            for (int j = 0; j < 16; ++j) {
                const float dx = __fsub_rn(px[j], L.x);
                const float dy = __fsub_rn(py[j], L.y);
                const float dz = __fsub_rn(pz[j], L.z);
                // ((dx^2 + dy^2) + dz^2), no FMA -> matches numpy fp32 (verified)
                const float d = __fadd_rn(__fadd_rn(__fmul_rn(dx, dx),
                                                    __fmul_rn(dy, dy)),
                                          __fmul_rn(dz, dz));
                const float dm = fminf(dmin[j], d);
                dmin[j] = dm;
                if (dm > bv) { bv = dm; bi = t * 16 + j; }   // strict > keeps lowest idx
            }

            u64 key = ((u64)__float_as_uint(bv) << 13) | (unsigned)(8191 - bi);
            key = dpp_max_u64<0x111>(key);   // row_shr:1
            key = dpp_max_u64<0x112>(key);   // row_shr:2
            key = dpp_max_u64<0x114>(key);   // row_shr:4
            key = dpp_max_u64<0x118>(key);   // row_shr:8
            key = dpp_max_u64<0x142>(key);   // row_bcast:15
            key = dpp_max_u64<0x143>(key);   // row_bcast:31 -> lane 63 = wave max

            const int buf = k & 1;                   // parity dbuf -> 1 barrier/iter
            if (lane == 63) keys[buf][w] = key;
            __syncthreads();

            const ulonglong2* kp = (const ulonglong2*)keys[buf];   // 4x ds_read_b128
            const ulonglong2 k0 = kp[0], k1 = kp[1], k2 = kp[2], k3 = kp[3];
            const u64 best = umax64(umax64(umax64(k0.x, k0.y), umax64(k1.x, k1.y)),
                                    umax64(umax64(k2.x, k2.y), umax64(k3.x, k3.y)));
            last = 8191 - (int)(best & 0x1FFFull);
        }
    } else {
        // ---------------- KNN consumers -------------------------------------
        const int kb = bid - NBATCH;                 // 0..239
        const int b  = kb / 15;                      // batch
        const int j  = kb % 15;                      // block-in-batch
        const int m0 = j * 8 + w;                    // 0..119 (wave's first query)

        const float* base = pc + (size_t)b * NPTS * 6;

        // stage the whole batch's xyz into this block's LDS (idle time:
        // happens before fps publishes anything)
#pragma unroll
        for (int jj = 0; jj < NPTS / 512; ++jj) {
            const int p = jj * 512 + t;
            sp[p] = make_float4(base[p * 6 + 0], base[p * 6 + 1],
                                base[p * 6 + 2], 0.0f);
        }
        __syncthreads();

        for (int m = m0; m < NGROUP; m += 120) {
            const int q = b * NGROUP + m;
            int rv;
            for (;;) {
                rv = __hip_atomic_load(rep + q, __ATOMIC_RELAXED,
                                       __HIP_MEMORY_SCOPE_AGENT);
                if (rv >= 0) break;
                __builtin_amdgcn_s_sleep(127);       // ~3.4us: 16x less poll traffic
            }
            knn_one(base, sp, out, q, rv, lane);
        }
    }
}

extern "C" void kernel_launch(void* const* d_in, const int* in_sizes, int n_in,
                              void* d_out, int out_size, void* d_ws, size_t ws_size,
                              hipStream_t stream) {
    const float* pc  = (const float*)d_in[0];
    float*       out = (float*)d_out;
    int*         rep = (int*)d_ws;                   // 32 KB

    // rep = -1 sentinels (0xFF bytes) — stream op, graph-capture-safe
    hipMemsetAsync(rep, 0xFF, (size_t)NBATCH * NGROUP * sizeof(int), stream);

    fused_kernel<<<NBATCH + 240, 512, 0, stream>>>(pc, rep, out);
}

// Round 19
// 571.851 us; speedup vs baseline: 1.1780x; 1.0190x over previous
//
#include <hip/hip_runtime.h>

#define NPTS   8192
#define NBATCH 16
#define NGROUP 512
#define GSIZE  32
#define BIGF   1e10f
#define KBLK   7          // consumer blocks per batch (was 15): halve active CUs

typedef unsigned long long u64;

// DPP max on a packed u64 key (round-7 proven).
template <int CTRL>
__device__ __forceinline__ u64 dpp_max_u64(u64 k) {
    const unsigned lo  = (unsigned)k;
    const unsigned hi  = (unsigned)(k >> 32);
    const unsigned slo = (unsigned)__builtin_amdgcn_update_dpp(0, (int)lo, CTRL, 0xF, 0xF, true);
    const unsigned shi = (unsigned)__builtin_amdgcn_update_dpp(0, (int)hi, CTRL, 0xF, 0xF, true);
    const u64 s = ((u64)shi << 32) | slo;
    return s > k ? s : k;
}

__device__ __forceinline__ u64 umax64(u64 a, u64 b) { return a > b ? a : b; }

// wave-uniform 64-bit readlane (SALU path, no LDS pipe)
__device__ __forceinline__ u64 rdlane64(u64 v, int l) {
    const unsigned lo = (unsigned)__builtin_amdgcn_readlane((int)(unsigned)v, l);
    const unsigned hi = (unsigned)__builtin_amdgcn_readlane((int)(unsigned)(v >> 32), l);
    return ((u64)hi << 32) | lo;
}

// ---------------------------------------------------------------------------
// knn scan for ONE query — r11 machinery (u64 keys = f64 bit order, readlane
// broadcasts, 2 points/lane/iter, lane-distributed sorted top-32) reading the
// block's LDS copy of the batch xyz. Bit-identical keys/order to r11.
// ---------------------------------------------------------------------------
__device__ __forceinline__ void knn_one(const float* __restrict__ base,
                                        const float4* sp,
                                        float* __restrict__ out,
                                        const int q, const int r, const int lane) {
    const float4 Q = sp[r];
    const float qxf = Q.x, qyf = Q.y, qzf = Q.z;
    const double qx = (double)qxf, qy = (double)qyf, qz = (double)qzf;

    const u64 INFB = 0x7ff0000000000000ull;
    u64 vk = INFB;  int vi = 0x7fffffff;
    u64 tauk = INFB;

    for (int i = 0; i < NPTS / 128; ++i) {
        const int p0 = i * 128 + lane;
        const float4 T0 = sp[p0];
        const float4 T1 = sp[p0 + 64];

        const double dx0 = qx - (double)T0.x;
        const double dy0 = qy - (double)T0.y;
        const double dz0 = qz - (double)T0.z;
        const u64 kd0 = __double_as_longlong(dx0 * dx0 + dy0 * dy0 + dz0 * dz0);
        const double dx1 = qx - (double)T1.x;
        const double dy1 = qy - (double)T1.y;
        const double dz1 = qz - (double)T1.z;
        const u64 kd1 = __double_as_longlong(dx1 * dx1 + dy1 * dy1 + dz1 * dz1);

        u64 m0 = __ballot(kd0 < tauk);
        const u64 m1pre = __ballot(kd1 < tauk);

        if (m0 | m1pre) {
            while (m0) {
                const int l = __ffsll(m0) - 1;
                m0 &= m0 - 1;
                const u64 xk = rdlane64(kd0, l);
                const int xi = i * 128 + l;
                const u64 pk = __shfl_up(vk, 1);
                const int pv = __shfl_up(vi, 1);
                const bool ltp = (lane > 0) && (xk < pk);
                const bool ltc = xk < vk;
                vk = ltp ? pk : (ltc ? xk : vk);
                vi = ltp ? pv : (ltc ? xi : vi);
            }
            tauk = rdlane64(vk, 31);
            u64 m1 = m1pre;
            while (m1) {
                const int l = __ffsll(m1) - 1;
                m1 &= m1 - 1;
                const u64 xk = rdlane64(kd1, l);
                if (xk < tauk) {
                    const int xi = i * 128 + 64 + l;
                    const u64 pk = __shfl_up(vk, 1);
                    const int pv = __shfl_up(vi, 1);
                    const bool ltp = (lane > 0) && (xk < pk);
                    const bool ltc = xk < vk;
                    vk = ltp ? pk : (ltc ? xk : vk);
                    vi = ltp ? pv : (ltc ? xi : vi);
                }
            }
            tauk = rdlane64(vk, 31);
        }
    }

    const size_t NBH = (size_t)NBATCH * NGROUP * GSIZE * 6;
    const size_t CEN = (size_t)NBATCH * NGROUP * 6;

    if (lane == 0) {
#pragma unroll
        for (int c = 0; c < 6; ++c)
            out[NBH + (size_t)q * 6 + c] = base[r * 6 + c];
    }
    if (lane < GSIZE) {
        const int n = vi;
        out[NBH + CEN + (size_t)q * GSIZE + lane] = (float)n;

        const float* np_ = base + (size_t)n * 6;
        const size_t o = ((size_t)q * GSIZE + lane) * 6;
        out[o + 0] = __fsub_rn(np_[0], qxf);
        out[o + 1] = __fsub_rn(np_[1], qyf);
        out[o + 2] = __fsub_rn(np_[2], qzf);
        out[o + 3] = np_[3];
        out[o + 4] = np_[4];
        out[o + 5] = np_[5];
    }
}

// ---------------------------------------------------------------------------
// Fused producer/consumer — r18 verbatim except consumer count: 7 blocks per
// batch (128 total blocks, 128 CUs idle). Decisive test of the last open
// theory for the ~46us fusion tax: chip-wide activity -> clock down-boost.
// (Read-BW falsified r16, poll-rate falsified r18, acquire-coherence
// falsified r17.) Drain capacity 56 wave-slots/batch = 5.6x arrival rate;
// tail unchanged (last query + one ~10us scan).
// ---------------------------------------------------------------------------
__global__ __launch_bounds__(512) void fused_kernel(const float* __restrict__ pc,
                                                    int* __restrict__ rep,
                                                    float* __restrict__ out) {
    const int bid  = blockIdx.x;
    const int t    = threadIdx.x;
    const int lane = t & 63;
    const int w    = t >> 6;

    __shared__ float4 sp[NPTS];                      // 128 KB
    __shared__ __align__(16) u64 keys[2][8];

    if (bid < NBATCH) {
        // ---------------- FPS producer (r11 body + per-iter publish) --------
        const int b = bid;
        const float* base = pc + (size_t)b * NPTS * 6;

        float px[16], py[16], pz[16], dmin[16];
#pragma unroll
        for (int j = 0; j < 16; ++j) {
            const int p = t * 16 + j;
            const float x = base[p * 6 + 0];
            const float y = base[p * 6 + 1];
            const float z = base[p * 6 + 2];
            px[j] = x; py[j] = y; pz[j] = z;
            sp[p] = make_float4(x, y, z, 0.0f);
            dmin[j] = BIGF;
        }
        __syncthreads();

        int last = 0;
        for (int k = 0; k < NGROUP; ++k) {
            if (t == 0)
                __hip_atomic_store(rep + b * NGROUP + k, last,
                                   __ATOMIC_RELAXED, __HIP_MEMORY_SCOPE_AGENT);
            if (k == NGROUP - 1) break;

            const float4 L = sp[last];               // one ds_read_b128, broadcast

            float bv = -1.0f;
            int   bi = 0;
#pragma unroll
            for (int j = 0; j < 16; ++j) {
                const float dx = __fsub_rn(px[j], L.x);
                const float dy = __fsub_rn(py[j], L.y);
                const float dz = __fsub_rn(pz[j], L.z);
                // ((dx^2 + dy^2) + dz^2), no FMA -> matches numpy fp32 (verified)
                const float d = __fadd_rn(__fadd_rn(__fmul_rn(dx, dx),
                                                    __fmul_rn(dy, dy)),
                                          __fmul_rn(dz, dz));
                const float dm = fminf(dmin[j], d);
                dmin[j] = dm;
                if (dm > bv) { bv = dm; bi = t * 16 + j; }   // strict > keeps lowest idx
            }

            u64 key = ((u64)__float_as_uint(bv) << 13) | (unsigned)(8191 - bi);
            key = dpp_max_u64<0x111>(key);   // row_shr:1
            key = dpp_max_u64<0x112>(key);   // row_shr:2
            key = dpp_max_u64<0x114>(key);   // row_shr:4
            key = dpp_max_u64<0x118>(key);   // row_shr:8
            key = dpp_max_u64<0x142>(key);   // row_bcast:15
            key = dpp_max_u64<0x143>(key);   // row_bcast:31 -> lane 63 = wave max

            const int buf = k & 1;                   // parity dbuf -> 1 barrier/iter
            if (lane == 63) keys[buf][w] = key;
            __syncthreads();

            const ulonglong2* kp = (const ulonglong2*)keys[buf];   // 4x ds_read_b128
            const ulonglong2 k0 = kp[0], k1 = kp[1], k2 = kp[2], k3 = kp[3];
            const u64 best = umax64(umax64(umax64(k0.x, k0.y), umax64(k1.x, k1.y)),
                                    umax64(umax64(k2.x, k2.y), umax64(k3.x, k3.y)));
            last = 8191 - (int)(best & 0x1FFFull);
        }
    } else {
        // ---------------- KNN consumers -------------------------------------
        const int kb = bid - NBATCH;                 // 0..NBATCH*KBLK-1
        const int b  = kb / KBLK;                    // batch
        const int j  = kb % KBLK;                    // block-in-batch
        const int m0 = j * 8 + w;                    // wave's first query
        const int stride = KBLK * 8;                 // 56 wave-slots per batch

        const float* base = pc + (size_t)b * NPTS * 6;

        // stage the whole batch's xyz into this block's LDS (idle time:
        // happens before fps publishes anything)
#pragma unroll
        for (int jj = 0; jj < NPTS / 512; ++jj) {
            const int p = jj * 512 + t;
            sp[p] = make_float4(base[p * 6 + 0], base[p * 6 + 1],
                                base[p * 6 + 2], 0.0f);
        }
        __syncthreads();

        for (int m = m0; m < NGROUP; m += stride) {
            const int q = b * NGROUP + m;
            int rv;
            for (;;) {
                rv = __hip_atomic_load(rep + q, __ATOMIC_RELAXED,
                                       __HIP_MEMORY_SCOPE_AGENT);
                if (rv >= 0) break;
                __builtin_amdgcn_s_sleep(127);
            }
            knn_one(base, sp, out, q, rv, lane);
        }
    }
}

extern "C" void kernel_launch(void* const* d_in, const int* in_sizes, int n_in,
                              void* d_out, int out_size, void* d_ws, size_t ws_size,
                              hipStream_t stream) {
    const float* pc  = (const float*)d_in[0];
    float*       out = (float*)d_out;
    int*         rep = (int*)d_ws;                   // 32 KB

    // rep = -1 sentinels (0xFF bytes) — stream op, graph-capture-safe
    hipMemsetAsync(rep, 0xFF, (size_t)NBATCH * NGROUP * sizeof(int), stream);

    fused_kernel<<<NBATCH + NBATCH * KBLK, 512, 0, stream>>>(pc, rep, out);
}